// Round 4
// baseline (421.984 us; speedup 1.0000x reference)
//
#include <hip/hip_runtime.h>
#include <math.h>

#define NN 50000
#define EE 800000
#define DIN 256
#define NEG_SLOPE 0.01f

typedef __attribute__((ext_vector_type(8))) short bf16x8;
typedef __attribute__((ext_vector_type(8))) unsigned short u16x8;
typedef __attribute__((ext_vector_type(4))) float f32x4;

__device__ __forceinline__ unsigned short bf16_rne(float f) {
    unsigned int u = __float_as_uint(f);
    u += 0x7fffu + ((u >> 16) & 1u);
    return (unsigned short)(u >> 16);
}
__device__ __forceinline__ float bf16_tof(unsigned short h) {
    return __uint_as_float(((unsigned int)h) << 16);
}

// ---------------------------------------------------------------------------
// CSR build
// ---------------------------------------------------------------------------
__global__ __launch_bounds__(256) void hist_kernel(const int* __restrict__ dst,
                                                   int* __restrict__ cnt, int E) {
    int e = blockIdx.x * 256 + threadIdx.x;
    if (e < E) atomicAdd(&cnt[dst[e]], 1);
}

__global__ __launch_bounds__(1024) void scanA_kernel(int* __restrict__ cnt,
                                                     int* __restrict__ off,
                                                     int* __restrict__ aux, int Nn) {
    __shared__ int wsums[16];
    int tid = threadIdx.x, lane = tid & 63, w = tid >> 6;
    int i = blockIdx.x * 1024 + tid;
    int v = (i < Nn) ? cnt[i] : 0;
    if (i < Nn) cnt[i] = 0;
    int x = v;
#pragma unroll
    for (int d = 1; d < 64; d <<= 1) {
        int y = __shfl_up(x, d);
        if (lane >= d) x += y;
    }
    if (lane == 63) wsums[w] = x;
    __syncthreads();
    if (w == 0 && lane < 16) {
        int ws = wsums[lane];
#pragma unroll
        for (int d = 1; d < 16; d <<= 1) {
            int y = __shfl_up(ws, d);
            if (lane >= d) ws += y;
        }
        wsums[lane] = ws;
    }
    __syncthreads();
    int incl = x + (w > 0 ? wsums[w - 1] : 0);
    if (i < Nn) off[i + 1] = incl;
    if (tid == 1023) aux[blockIdx.x] = incl;
}

__global__ __launch_bounds__(1024) void scanC_kernel(const int* __restrict__ aux,
                                                     int* __restrict__ off, int Nn) {
    int b = blockIdx.x;
    int prefix = 0;
    for (int j = 0; j < b; j++) prefix += aux[j];
    int i = b * 1024 + threadIdx.x;
    if (i < Nn) off[i + 1] += prefix;
    if (i == 0 && b == 0) off[0] = 0;
}

__global__ __launch_bounds__(256) void scatter_kernel(const int* __restrict__ src,
                                                      const int* __restrict__ dst,
                                                      const int* __restrict__ off,
                                                      int* __restrict__ cnt,
                                                      int* __restrict__ esrc, int E) {
    int e = blockIdx.x * 256 + threadIdx.x;
    if (e >= E) return;
    int d = dst[e];
    int pos = atomicAdd(&cnt[d], 1);
    esrc[off[d] + pos] = src[e];
}

// ---------------------------------------------------------------------------
// One-shot weight convert + transpose: W[H][D][64] -> Wt hi/lo [H*64][D]
// ---------------------------------------------------------------------------
__global__ __launch_bounds__(256) void conv_w_kernel(
    const float* __restrict__ W0, const float* __restrict__ W1,
    const float* __restrict__ Wf, unsigned short* __restrict__ w0h,
    unsigned short* __restrict__ w0l, unsigned short* __restrict__ w1h,
    unsigned short* __restrict__ w1l, unsigned short* __restrict__ wfh,
    unsigned short* __restrict__ wfl) {
    int t = blockIdx.x * 256 + threadIdx.x;
    const float* W;
    unsigned short *oh, *ol;
    int D, u;
    if (t < 32768) { W = W0; oh = w0h; ol = w0l; D = 256; u = t; }
    else if (t < 49152) { W = W1; oh = w1h; ol = w1l; D = 128; u = t - 32768; }
    else if (t < 57344) { W = Wf; oh = wfh; ol = wfl; D = 128; u = t - 49152; }
    else return;
    int d = u & (D - 1);
    int n = u / D;
    float v = W[((size_t)(n >> 6) * D + d) * 64 + (n & 63)];
    unsigned short hi = bf16_rne(v);
    unsigned short lo = bf16_rne(v - bf16_tof(hi));
    oh[(size_t)n * D + d] = hi;
    ol[(size_t)n * D + d] = lo;
}

// ---------------------------------------------------------------------------
// MFMA bf16x3 GEMM + fused attention dots. M-tile 64, N = NCOL (all heads).
//   AFP32: A staged from fp32 (layer 0); else from preconverted hi/lo.
// grid = ceil(N/64); block 256 (4 waves); wave tile 16 x NCOL.
// ---------------------------------------------------------------------------
#define LDK 40

template <int NCOL, bool AFP32>
__global__ __launch_bounds__(256) void gemm_attn(
    const float* __restrict__ Xf, const unsigned short* __restrict__ Xhi,
    const unsigned short* __restrict__ Xlo, const unsigned short* __restrict__ Wthi,
    const unsigned short* __restrict__ Wtlo, const float* __restrict__ bias,
    const float* __restrict__ al, const float* __restrict__ bl,
    const float* __restrict__ ar, const float* __restrict__ br,
    float* __restrict__ FT, float* __restrict__ A1, float* __restrict__ A2,
    int Nn, int D) {
    const int H = NCOL / 64;
    const int NC16 = NCOL / 16;
    __shared__ __align__(16) unsigned short Ahi_s[64 * LDK];
    __shared__ __align__(16) unsigned short Alo_s[64 * LDK];
    __shared__ __align__(16) unsigned short Bhi_s[NCOL * LDK];
    __shared__ __align__(16) unsigned short Blo_s[NCOL * LDK];

    int tid = threadIdx.x;
    int wv = tid >> 6, l = tid & 63, lm = l & 15, quad = l >> 4;
    int m0 = blockIdx.x * 64;

    f32x4 acc[NC16];
#pragma unroll
    for (int c = 0; c < NC16; c++) acc[c] = (f32x4){0.f, 0.f, 0.f, 0.f};

    for (int d0 = 0; d0 < D; d0 += 32) {
        if (AFP32) {
            // 64 rows x 32 k fp32 -> hi/lo, 512 float4 units
#pragma unroll
            for (int i = 0; i < 2; i++) {
                int u = tid + i * 256;
                int row = u >> 3, c4 = u & 7;
                float4 v = make_float4(0.f, 0.f, 0.f, 0.f);
                if (m0 + row < Nn)
                    v = *(const float4*)&Xf[(size_t)(m0 + row) * D + d0 + c4 * 4];
                float f[4] = {v.x, v.y, v.z, v.w};
                unsigned short hi[4], lo[4];
#pragma unroll
                for (int j = 0; j < 4; j++) {
                    hi[j] = bf16_rne(f[j]);
                    lo[j] = bf16_rne(f[j] - bf16_tof(hi[j]));
                }
                *(ushort4*)&Ahi_s[row * LDK + c4 * 4] = make_ushort4(hi[0], hi[1], hi[2], hi[3]);
                *(ushort4*)&Alo_s[row * LDK + c4 * 4] = make_ushort4(lo[0], lo[1], lo[2], lo[3]);
            }
        } else {
            // 256 ushort8 units (row = tid>>2, q = tid&3)
            int row = tid >> 2, q = tid & 3;
            u16x8 vh = (u16x8)0, vl = (u16x8)0;
            if (m0 + row < Nn) {
                vh = *(const u16x8*)&Xhi[(size_t)(m0 + row) * D + d0 + q * 8];
                vl = *(const u16x8*)&Xlo[(size_t)(m0 + row) * D + d0 + q * 8];
            }
            *(u16x8*)&Ahi_s[row * LDK + q * 8] = vh;
            *(u16x8*)&Alo_s[row * LDK + q * 8] = vl;
        }
        // B: NCOL rows x 32 k
#pragma unroll
        for (int i = 0; i < NCOL / 64; i++) {
            int u = tid + i * 256;
            int n = u >> 2, q = u & 3;
            *(u16x8*)&Bhi_s[n * LDK + q * 8] =
                *(const u16x8*)&Wthi[(size_t)n * D + d0 + q * 8];
            *(u16x8*)&Blo_s[n * LDK + q * 8] =
                *(const u16x8*)&Wtlo[(size_t)n * D + d0 + q * 8];
        }
        __syncthreads();

        int arow = wv * 16 + lm;
        bf16x8 ah = *(const bf16x8*)&Ahi_s[arow * LDK + quad * 8];
        bf16x8 alo = *(const bf16x8*)&Alo_s[arow * LDK + quad * 8];
#pragma unroll
        for (int c = 0; c < NC16; c++) {
            bf16x8 bh = *(const bf16x8*)&Bhi_s[(c * 16 + lm) * LDK + quad * 8];
            bf16x8 blo = *(const bf16x8*)&Blo_s[(c * 16 + lm) * LDK + quad * 8];
            acc[c] = __builtin_amdgcn_mfma_f32_16x16x32_bf16(ah, bh, acc[c], 0, 0, 0);
            acc[c] = __builtin_amdgcn_mfma_f32_16x16x32_bf16(ah, blo, acc[c], 0, 0, 0);
            acc[c] = __builtin_amdgcn_mfma_f32_16x16x32_bf16(alo, bh, acc[c], 0, 0, 0);
        }
        __syncthreads();
    }

    float bj[NC16], alj[NC16], arj[NC16];
#pragma unroll
    for (int c = 0; c < NC16; c++) {
        bj[c] = bias[c * 16 + lm];
        alj[c] = al[c * 16 + lm];
        arj[c] = ar[c * 16 + lm];
    }
#pragma unroll
    for (int reg = 0; reg < 4; reg++) {
        int row = m0 + wv * 16 + quad * 4 + reg;
        bool ok = row < Nn;
        float s1[H], s2[H];
#pragma unroll
        for (int h = 0; h < H; h++) { s1[h] = 0.f; s2[h] = 0.f; }
#pragma unroll
        for (int c = 0; c < NC16; c++) {
            float o = acc[c][reg] + bj[c];
            int h = c >> 2;
            s1[h] += o * alj[c];
            s2[h] += o * arj[c];
            if (ok) FT[(size_t)row * NCOL + c * 16 + lm] = o;
        }
#pragma unroll
        for (int h = 0; h < H; h++) {
#pragma unroll
            for (int d = 1; d < 16; d <<= 1) {
                s1[h] += __shfl_xor(s1[h], d);
                s2[h] += __shfl_xor(s2[h], d);
            }
        }
        if (ok && lm == 0) {
#pragma unroll
            for (int h = 0; h < H; h++) {
                A1[(size_t)row * H + h] = s1[h] + bl[h];
                A2[(size_t)row * H + h] = s2[h] + br[h];
            }
        }
    }
}

// ---------------------------------------------------------------------------
// Edge softmax + aggregation + ELU, one wave per dst node, online softmax.
// H=2: float4 gather, 2 edges per instruction; output written as bf16 hi/lo.
// ---------------------------------------------------------------------------
__global__ __launch_bounds__(256) void edge_agg2_kernel(
    const float* __restrict__ ft, const float* __restrict__ a1,
    const float* __restrict__ a2, const int* __restrict__ off,
    const int* __restrict__ esrc, unsigned short* __restrict__ ohi,
    unsigned short* __restrict__ olo, int Nn) {
    __shared__ __align__(16) float ws[4][64];
    __shared__ __align__(16) int sjs[4][32];
    int wv = threadIdx.x >> 6, lane = threadIdx.x & 63;
    int n = blockIdx.x * 4 + wv;
    if (n >= Nn) return;
    int o0 = off[n], deg = off[n + 1] - o0;
    int hs = lane >> 5, el = lane & 31;
    int g = lane >> 5, cl = lane & 31, hg = cl >> 4;
    if (deg == 0) {
        if (lane < 32) {
            *(ushort4*)&ohi[(size_t)n * 128 + cl * 4] = make_ushort4(0, 0, 0, 0);
            *(ushort4*)&olo[(size_t)n * 128 + cl * 4] = make_ushort4(0, 0, 0, 0);
        }
        return;
    }
    float a1v = a1[(size_t)n * 2 + hs];
    float m = -1e30f, dsum = 0.f;
    float ax = 0.f, ay = 0.f, az = 0.f, aw = 0.f;

    for (int e0 = 0; e0 < deg; e0 += 32) {
        int nE = min(32, deg - e0);
        int sj = 0;
        float s = -1e30f;
        if (el < nE) {
            sj = esrc[o0 + e0 + el];
            float t = a1v + a2[(size_t)sj * 2 + hs];
            s = t > 0.f ? t : NEG_SLOPE * t;
        }
        float cm = s;
#pragma unroll
        for (int d = 1; d < 32; d <<= 1) cm = fmaxf(cm, __shfl_xor(cm, d));
        float nm = fmaxf(m, cm);
        float scale = __expf(m - nm);
        float wgt = (el < nE) ? __expf(s - nm) : 0.f;
        float csum = wgt;
#pragma unroll
        for (int d = 1; d < 32; d <<= 1) csum += __shfl_xor(csum, d);
        dsum = dsum * scale + csum;
        m = nm;
        float scg = __shfl(scale, hg * 32);
        ax *= scg; ay *= scg; az *= scg; aw *= scg;
        ws[wv][hs * 32 + el] = wgt;
        if (hs == 0 && el < nE) sjs[wv][el] = sj;

#define PAIR2(J)                                                              \
    {                                                                         \
        int jj = (J) + g;                                                     \
        float w = (jj < nE) ? ws[wv][hg * 32 + jj] : 0.f;                     \
        int s0 = sjs[wv][jj < nE ? jj : 0];                                   \
        const float4 f = *(const float4*)&ft[(size_t)s0 * 128 + cl * 4];      \
        ax += w * f.x; ay += w * f.y; az += w * f.z; aw += w * f.w;           \
    }
        int j = 0;
        for (; j + 8 <= nE; j += 8) { PAIR2(j); PAIR2(j + 2); PAIR2(j + 4); PAIR2(j + 6); }
        for (; j < nE; j += 2) PAIR2(j);
#undef PAIR2
    }
    ax += __shfl_xor(ax, 32);
    ay += __shfl_xor(ay, 32);
    az += __shfl_xor(az, 32);
    aw += __shfl_xor(aw, 32);
    float dg = __shfl(dsum, hg * 32);
    if (lane < 32) {
        float rd = 1.f / dg;
        float r[4] = {ax * rd, ay * rd, az * rd, aw * rd};
        unsigned short hi[4], lo[4];
#pragma unroll
        for (int k = 0; k < 4; k++) {
            float v = r[k] > 0.f ? r[k] : expm1f(r[k]);
            hi[k] = bf16_rne(v);
            lo[k] = bf16_rne(v - bf16_tof(hi[k]));
        }
        *(ushort4*)&ohi[(size_t)n * 128 + cl * 4] = make_ushort4(hi[0], hi[1], hi[2], hi[3]);
        *(ushort4*)&olo[(size_t)n * 128 + cl * 4] = make_ushort4(lo[0], lo[1], lo[2], lo[3]);
    }
}

// H=1: float4 gather, 4 edges per instruction; fp32 output (d_out).
__global__ __launch_bounds__(256) void edge_agg1_kernel(
    const float* __restrict__ ft, const float* __restrict__ a1,
    const float* __restrict__ a2, const int* __restrict__ off,
    const int* __restrict__ esrc, float* __restrict__ out, int Nn) {
    __shared__ __align__(16) float ws[4][64];
    __shared__ __align__(16) int sjs[4][64];
    int wv = threadIdx.x >> 6, lane = threadIdx.x & 63;
    int n = blockIdx.x * 4 + wv;
    if (n >= Nn) return;
    int o0 = off[n], deg = off[n + 1] - o0;
    int g4 = lane >> 4, cl = lane & 15;
    if (deg == 0) {
        if (lane < 16) *(float4*)&out[(size_t)n * 64 + cl * 4] = make_float4(0, 0, 0, 0);
        return;
    }
    float a1v = a1[n];
    float m = -1e30f, dsum = 0.f;
    float ax = 0.f, ay = 0.f, az = 0.f, aw = 0.f;
    for (int e0 = 0; e0 < deg; e0 += 64) {
        int nE = min(64, deg - e0);
        int sj = 0;
        float s = -1e30f;
        if (lane < nE) {
            sj = esrc[o0 + e0 + lane];
            float t = a1v + a2[sj];
            s = t > 0.f ? t : NEG_SLOPE * t;
        }
        float cm = s;
#pragma unroll
        for (int d = 1; d < 64; d <<= 1) cm = fmaxf(cm, __shfl_xor(cm, d));
        float nm = fmaxf(m, cm);
        float scale = __expf(m - nm);
        float wgt = (lane < nE) ? __expf(s - nm) : 0.f;
        float csum = wgt;
#pragma unroll
        for (int d = 1; d < 64; d <<= 1) csum += __shfl_xor(csum, d);
        dsum = dsum * scale + csum;
        m = nm;
        ax *= scale; ay *= scale; az *= scale; aw *= scale;
        ws[wv][lane] = wgt;
        if (lane < nE) sjs[wv][lane] = sj;

#define QUAD1(J)                                                              \
    {                                                                         \
        int jj = (J) + g4;                                                    \
        float w = (jj < nE) ? ws[wv][jj] : 0.f;                               \
        int s0 = sjs[wv][jj < nE ? jj : 0];                                   \
        const float4 f = *(const float4*)&ft[(size_t)s0 * 64 + cl * 4];       \
        ax += w * f.x; ay += w * f.y; az += w * f.z; aw += w * f.w;           \
    }
        int j = 0;
        for (; j + 16 <= nE; j += 16) { QUAD1(j); QUAD1(j + 4); QUAD1(j + 8); QUAD1(j + 12); }
        for (; j < nE; j += 4) QUAD1(j);
#undef QUAD1
    }
#pragma unroll
    for (int d = 16; d < 64; d <<= 1) {
        ax += __shfl_xor(ax, d);
        ay += __shfl_xor(ay, d);
        az += __shfl_xor(az, d);
        aw += __shfl_xor(aw, d);
    }
    if (lane < 16) {
        float rd = 1.f / dsum;
        float4 r = make_float4(ax * rd, ay * rd, az * rd, aw * rd);
        r.x = r.x > 0.f ? r.x : expm1f(r.x);
        r.y = r.y > 0.f ? r.y : expm1f(r.y);
        r.z = r.z > 0.f ? r.z : expm1f(r.z);
        r.w = r.w > 0.f ? r.w : expm1f(r.w);
        *(float4*)&out[(size_t)n * 64 + cl * 4] = r;
    }
}

// ---------------------------------------------------------------------------
// launch
// ---------------------------------------------------------------------------
extern "C" void kernel_launch(void* const* d_in, const int* in_sizes, int n_in,
                              void* d_out, int out_size, void* d_ws, size_t ws_size,
                              hipStream_t stream) {
    const float* features = (const float*)d_in[0];
    const int* src = (const int*)d_in[1];
    const int* dst = (const int*)d_in[2];
    const float* W0 = (const float*)d_in[3];
    const float* b0 = (const float*)d_in[4];
    const float* al0 = (const float*)d_in[5];
    const float* bl0 = (const float*)d_in[6];
    const float* ar0 = (const float*)d_in[7];
    const float* br0 = (const float*)d_in[8];
    const float* W1 = (const float*)d_in[9];
    const float* b1 = (const float*)d_in[10];
    const float* al1 = (const float*)d_in[11];
    const float* bl1 = (const float*)d_in[12];
    const float* ar1 = (const float*)d_in[13];
    const float* br1 = (const float*)d_in[14];
    const float* Wf = (const float*)d_in[15];
    const float* bf = (const float*)d_in[16];
    const float* alf = (const float*)d_in[17];
    const float* blf = (const float*)d_in[18];
    const float* arf = (const float*)d_in[19];
    const float* brf = (const float*)d_in[20];

    char* p = (char*)d_ws;
    auto carve = [&](size_t bytes) {
        void* q = (void*)p;
        p += (bytes + 255) & ~(size_t)255;
        return q;
    };
    float* ft = (float*)carve((size_t)NN * 128 * 4);
    unsigned short* Xhi = (unsigned short*)carve((size_t)NN * 128 * 2);
    unsigned short* Xlo = (unsigned short*)carve((size_t)NN * 128 * 2);
    float* a1 = (float*)carve((size_t)NN * 2 * 4);
    float* a2 = (float*)carve((size_t)NN * 2 * 4);
    int* off = (int*)carve((size_t)(NN + 1) * 4);
    int* cnt = (int*)carve((size_t)NN * 4);
    int* esrc = (int*)carve((size_t)EE * 4);
    int* aux = (int*)carve(64 * 4);
    unsigned short* w0h = (unsigned short*)carve(32768 * 2);
    unsigned short* w0l = (unsigned short*)carve(32768 * 2);
    unsigned short* w1h = (unsigned short*)carve(16384 * 2);
    unsigned short* w1l = (unsigned short*)carve(16384 * 2);
    unsigned short* wfh = (unsigned short*)carve(8192 * 2);
    unsigned short* wfl = (unsigned short*)carve(8192 * 2);

    const int NB_SCAN = (NN + 1023) / 1024;

    // ---- CSR build + weight convert ----
    hipMemsetAsync(cnt, 0, (size_t)NN * 4, stream);
    hist_kernel<<<(EE + 255) / 256, 256, 0, stream>>>(dst, cnt, EE);
    scanA_kernel<<<NB_SCAN, 1024, 0, stream>>>(cnt, off, aux, NN);
    scanC_kernel<<<NB_SCAN, 1024, 0, stream>>>(aux, off, NN);
    scatter_kernel<<<(EE + 255) / 256, 256, 0, stream>>>(src, dst, off, cnt, esrc, EE);
    conv_w_kernel<<<(57344 + 255) / 256, 256, 0, stream>>>(W0, W1, Wf, w0h, w0l, w1h,
                                                           w1l, wfh, wfl);

    const int gx = (NN + 63) / 64;
    const int gn = (NN + 3) / 4;

    // ---- layer 0: D=256, H=2 (fp32 A) ----
    gemm_attn<128, true><<<gx, 256, 0, stream>>>(features, nullptr, nullptr, w0h, w0l,
                                                 b0, al0, bl0, ar0, br0, ft, a1, a2,
                                                 NN, DIN);
    edge_agg2_kernel<<<gn, 256, 0, stream>>>(ft, a1, a2, off, esrc, Xhi, Xlo, NN);

    // ---- layer 1: D=128, H=2 (bf16 A) ----
    gemm_attn<128, false><<<gx, 256, 0, stream>>>(nullptr, Xhi, Xlo, w1h, w1l, b1, al1,
                                                  bl1, ar1, br1, ft, a1, a2, NN, 128);
    edge_agg2_kernel<<<gn, 256, 0, stream>>>(ft, a1, a2, off, esrc, Xhi, Xlo, NN);

    // ---- final layer: D=128, H=1 ----
    gemm_attn<64, false><<<gx, 256, 0, stream>>>(nullptr, Xhi, Xlo, wfh, wfl, bf, alf,
                                                 blf, arf, brf, ft, a1, a2, NN, 128);
    edge_agg1_kernel<<<gn, 256, 0, stream>>>(ft, a1, a2, off, esrc, (float*)d_out, NN);
}